// Round 4
// baseline (55.641 us; speedup 1.0000x reference)
//
#include <hip/hip_runtime.h>
#include <hip/hip_bf16.h>

#define BATCH 16
#define CHAN  256
#define HW    16384
#define NCLS  6

typedef float  f32x4 __attribute__((ext_vector_type(4)));
typedef int    i32x4 __attribute__((ext_vector_type(4)));

// Kernel 1: per-batch class inverse-counts -> d_ws (BATCH*NCLS floats).
// One block per batch; 256 threads x 16 int4 = 16384 labels.
__global__ __launch_bounds__(256)
void count_kernel(const int* __restrict__ gt, float* __restrict__ invcnt) {
    const int b = blockIdx.x;
    const int t = threadIdx.x;
    const int* __restrict__ gp = gt + (size_t)b * HW;

    int cnt[NCLS];
#pragma unroll
    for (int k = 0; k < NCLS; ++k) cnt[k] = 0;

#pragma unroll
    for (int i = 0; i < 16; ++i) {
        const i32x4 L = *reinterpret_cast<const i32x4*>(gp + i * 1024 + t * 4);
#pragma unroll
        for (int k = 0; k < NCLS; ++k)
            cnt[k] += (L.x == k) + (L.y == k) + (L.z == k) + (L.w == k);
    }

#pragma unroll
    for (int off = 32; off >= 1; off >>= 1)
#pragma unroll
        for (int k = 0; k < NCLS; ++k) cnt[k] += __shfl_xor(cnt[k], off, 64);

    __shared__ int lc[4][NCLS];
    const int wave = t >> 6, lane = t & 63;
    if (lane == 0)
#pragma unroll
        for (int k = 0; k < NCLS; ++k) lc[wave][k] = cnt[k];
    __syncthreads();

    if (t < NCLS) {
        const int csum = lc[0][t] + lc[1][t] + lc[2][t] + lc[3][t];
        invcnt[b * NCLS + t] = 1.0f / (float)((csum > 1) ? csum : 1);
    }
}

// Kernel 2: one block per (b,c). 256 threads, 64 pixels/thread, float4/int4.
// Per-class select-accumulate (no counts), wave reduce, scale by invcnt.
__global__ __launch_bounds__(256)
void gt2center_kernel(const float* __restrict__ x,
                      const int*   __restrict__ gt,
                      const float* __restrict__ invcnt,
                      float*       __restrict__ out) {
    const int bc = blockIdx.x;          // b*CHAN + c
    const int b  = bc >> 8;             // CHAN == 256
    const int c  = bc & 255;
    const float* __restrict__ xp = x  + (size_t)bc * HW;
    const int*   __restrict__ gp = gt + (size_t)b  * HW;
    const int t = threadIdx.x;

    float s[NCLS];
#pragma unroll
    for (int k = 0; k < NCLS; ++k) s[k] = 0.0f;

#pragma unroll
    for (int i = 0; i < 16; ++i) {
        const int n = i * 1024 + t * 4;
        // x is a 256 MiB read-once stream: nontemporal, don't pollute L2/L3.
        const f32x4 v = __builtin_nontemporal_load(
            reinterpret_cast<const f32x4*>(xp + n));
        // gt is reused by 256 blocks per batch: keep cached.
        const i32x4 L = *reinterpret_cast<const i32x4*>(gp + n);
#pragma unroll
        for (int k = 0; k < NCLS; ++k) {
            s[k] += (L.x == k) ? v.x : 0.0f;
            s[k] += (L.y == k) ? v.y : 0.0f;
            s[k] += (L.z == k) ? v.z : 0.0f;
            s[k] += (L.w == k) ? v.w : 0.0f;
        }
    }

#pragma unroll
    for (int off = 32; off >= 1; off >>= 1)
#pragma unroll
        for (int k = 0; k < NCLS; ++k)
            s[k] += __shfl_xor(s[k], off, 64);

    __shared__ float ls[4][NCLS];
    const int wave = t >> 6, lane = t & 63;
    if (lane == 0)
#pragma unroll
        for (int k = 0; k < NCLS; ++k) ls[wave][k] = s[k];
    __syncthreads();

    if (t < NCLS) {
        const float ssum = ls[0][t] + ls[1][t] + ls[2][t] + ls[3][t];
        out[((size_t)b * NCLS + t) * CHAN + c] = ssum * invcnt[b * NCLS + t];
    }
}

extern "C" void kernel_launch(void* const* d_in, const int* in_sizes, int n_in,
                              void* d_out, int out_size, void* d_ws, size_t ws_size,
                              hipStream_t stream) {
    const float* x   = (const float*)d_in[0];
    const int*   gt  = (const int*)d_in[1];
    float*       out = (float*)d_out;
    float*       invcnt = (float*)d_ws;   // BATCH*NCLS floats

    count_kernel<<<BATCH, 256, 0, stream>>>(gt, invcnt);
    gt2center_kernel<<<BATCH * CHAN, 256, 0, stream>>>(x, gt, invcnt, out);
}

// Round 5
// 53.151 us; speedup vs baseline: 1.0468x; 1.0468x over previous
//
#include <hip/hip_runtime.h>
#include <hip/hip_bf16.h>

#define BATCH 16
#define CHAN  256
#define HW    16384
#define NCLS  6

typedef float  f32x4 __attribute__((ext_vector_type(4)));
typedef int    i32x4 __attribute__((ext_vector_type(4)));

// One block per (b,c). 256 threads; 64 pixels/thread as 16 iterations of
// float4/int4, unrolled 4x (bounded VGPR -> higher occupancy -> more
// outstanding HBM loads). Per-class select-accumulate + counts in-loop,
// wave butterfly reduce, cross-wave LDS reduce, write out[b][k][c].
__global__ __launch_bounds__(256)
void gt2center_kernel(const float* __restrict__ x,
                      const int*   __restrict__ gt,
                      float*       __restrict__ out) {
    const int bc = blockIdx.x;          // b*CHAN + c
    const int b  = bc >> 8;             // CHAN == 256
    const int c  = bc & 255;
    const float* __restrict__ xp = x  + (size_t)bc * HW;
    const int*   __restrict__ gp = gt + (size_t)b  * HW;
    const int t = threadIdx.x;

    float s[NCLS];
    int   cnt[NCLS];
#pragma unroll
    for (int k = 0; k < NCLS; ++k) { s[k] = 0.0f; cnt[k] = 0; }

#pragma unroll 4
    for (int i = 0; i < 16; ++i) {
        const int n = i * 1024 + t * 4;
        const f32x4 v = *reinterpret_cast<const f32x4*>(xp + n);
        const i32x4 L = *reinterpret_cast<const i32x4*>(gp + n);
#pragma unroll
        for (int k = 0; k < NCLS; ++k) {
            s[k] += (L.x == k) ? v.x : 0.0f;
            s[k] += (L.y == k) ? v.y : 0.0f;
            s[k] += (L.z == k) ? v.z : 0.0f;
            s[k] += (L.w == k) ? v.w : 0.0f;
            cnt[k] += (L.x == k) + (L.y == k) + (L.z == k) + (L.w == k);
        }
    }

    // 64-lane butterfly reduce
#pragma unroll
    for (int off = 32; off >= 1; off >>= 1) {
#pragma unroll
        for (int k = 0; k < NCLS; ++k) {
            s[k]   += __shfl_xor(s[k],   off, 64);
            cnt[k] += __shfl_xor(cnt[k], off, 64);
        }
    }

    __shared__ float ls[4][NCLS];
    __shared__ int   lc[4][NCLS];
    const int wave = t >> 6, lane = t & 63;
    if (lane == 0) {
#pragma unroll
        for (int k = 0; k < NCLS; ++k) { ls[wave][k] = s[k]; lc[wave][k] = cnt[k]; }
    }
    __syncthreads();

    if (t < NCLS) {
        const float ssum = ls[0][t] + ls[1][t] + ls[2][t] + ls[3][t];
        const int   csum = lc[0][t] + lc[1][t] + lc[2][t] + lc[3][t];
        const float d = (csum > 1) ? (float)csum : 1.0f;
        out[((size_t)b * NCLS + t) * CHAN + c] = ssum / d;
    }
}

extern "C" void kernel_launch(void* const* d_in, const int* in_sizes, int n_in,
                              void* d_out, int out_size, void* d_ws, size_t ws_size,
                              hipStream_t stream) {
    const float* x   = (const float*)d_in[0];
    const int*   gt  = (const int*)d_in[1];
    float*       out = (float*)d_out;
    gt2center_kernel<<<BATCH * CHAN, 256, 0, stream>>>(x, gt, out);
}